// Round 3
// baseline (8339.547 us; speedup 1.0000x reference)
//
#include <hip/hip_runtime.h>

typedef unsigned int u32;
typedef unsigned short u16;
typedef _Float16 half2_t __attribute__((ext_vector_type(2)));

#define TM 94          // T_MOD
#define NB 4           // batches per decoder block
#define DEC_NT 512

// ---------- helpers ----------
__device__ __forceinline__ float bf2f(u16 v){ return __builtin_bit_cast(float, ((u32)v)<<16); }
__device__ __forceinline__ float bflo(u32 v){ return __builtin_bit_cast(float, v<<16); }
__device__ __forceinline__ float bfhi(u32 v){ return __builtin_bit_cast(float, v & 0xffff0000u); }
__device__ __forceinline__ u32 f2bf_bits(float f){ u32 u=__builtin_bit_cast(u32,f); return (u + 0x7fffu + ((u>>16)&1u))>>16; }
__device__ __forceinline__ u32 packbf2(float a, float b){ return f2bf_bits(a) | (f2bf_bits(b)<<16); }
__device__ __forceinline__ u32 packh2(float a, float b){ half2_t h; h.x=(_Float16)a; h.y=(_Float16)b; return __builtin_bit_cast(u32,h); }
__device__ __forceinline__ float fdot2(u32 a, u32 b, float c){
  return __builtin_amdgcn_fdot2(__builtin_bit_cast(half2_t,a), __builtin_bit_cast(half2_t,b), c, false);
}
__device__ __forceinline__ float fast_rcp(float x){ return __builtin_amdgcn_rcpf(x); }
__device__ __forceinline__ float sigmoid_f(float x){ return fast_rcp(1.f + __expf(-x)); }
__device__ __forceinline__ float tanh_f(float x){ float e=__expf(2.f*x); return 1.f - 2.f*fast_rcp(e+1.f); }

// ---------- kernel 1: conv + relu -> H (bf16) ----------
__global__ __launch_bounds__(128)
void conv_kernel(const float* __restrict__ enc, const float* __restrict__ cw,
                 const float* __restrict__ cb, u16* __restrict__ Hb)
{
  __shared__ float sE[8100];
  const int tid = threadIdx.x;
  const int b = blockIdx.y;
  const int chunk = blockIdx.x;      // 10 chunks of 10 m's
  const float* ep = enc + (size_t)b*8100;
  for (int i=tid;i<8100;i+=128) sE[i]=ep[i];
  __syncthreads();
  if (tid >= TM) return;
  const int t = tid;
  const int mo = chunk*10;
  const float* wb = cw + mo*567;     // block-uniform -> scalar loads
  float acc[10];
  #pragma unroll
  for (int k=0;k<10;k++) acc[k]=cb[mo+k];
  const float* e = sE + t*81;
  #pragma unroll 3
  for (int j=0;j<567;j++){
    float ev = e[j];
    #pragma unroll
    for (int k=0;k<10;k++) acc[k] += ev*wb[k*567+j];
  }
  u32* out = (u32*)Hb + ((size_t)b*9400 + t*100 + mo)/2;
  #pragma unroll
  for (int k=0;k<5;k++) out[k] = packbf2(fmaxf(acc[2*k],0.f), fmaxf(acc[2*k+1],0.f));
}

// ---------- kernel 2: persistent decoder, NB=4 batches/block ----------
// dynamic LDS layout (bytes):
#define OFF_SHU   75200     // sHU  [4][94][100] bf16
#define OFF_SQ2   152448    // q f16 [4][256] (d|s)
#define OFF_SA    154496    // a fp32 [4][100]
#define OFF_SB    156096    // beta fp32 [4][96]
#define OFF_SC2   157632    // c f16 [4][104]
#define OFF_SG    158464    // gates f16 [4][512]
#define OFF_SVD   162560    // vd fp32 [100]
#define DEC_LDS   162960

// waves_per_eu pinned to (2,2): LDS caps us at 1 block/CU = 2 waves/SIMD anyway;
// without the max-pin LLVM targets 4 waves/EU (128 VGPRs) and spills the
// register-resident weights into the 94-step loop (round-2: 46 MB scratch writes).
__global__ __launch_bounds__(DEC_NT)
__attribute__((amdgpu_waves_per_eu(2, 2)))
void decoder_kernel(const u16* __restrict__ Hb, const float* __restrict__ Wd,
                    const float* __restrict__ Ud, const float* __restrict__ vd,
                    const float* __restrict__ wih, const float* __restrict__ whh,
                    const float* __restrict__ bih, const float* __restrict__ bhh,
                    float* __restrict__ dT, float* __restrict__ cLast)
{
  extern __shared__ char smem[];
  u16*      sH   = (u16*)smem;                       // [4][94][100] bf16
  u16*      sHU  = (u16*)(smem + OFF_SHU);
  _Float16* sq2  = (_Float16*)(smem + OFF_SQ2);
  float*    sa   = (float*)(smem + OFF_SA);
  float*    sbeta= (float*)(smem + OFF_SB);
  u32*      sc2  = (u32*)(smem + OFF_SC2);           // f16 pairs
  _Float16* sg   = (_Float16*)(smem + OFF_SG);
  float*    svd  = (float*)(smem + OFF_SVD);

  const int tid = threadIdx.x;
  const int b0 = blockIdx.x * NB;

  // stage H (4 batches): 4*9400 bf16 = 4700 uint4
  {
    const uint4* src = (const uint4*)(Hb + (size_t)b0*9400);
    uint4* dst = (uint4*)sH;
    for (int i=tid;i<4700;i+=DEC_NT) dst[i]=src[i];
  }
  if (tid < 100) svd[tid] = vd[tid];
  {
    u32* q2 = (u32*)sq2;
    for (int i=tid;i<NB*128;i+=DEC_NT) q2[i]=0u;
  }
  __syncthreads();

  // HU[bi][t][k] = sum_m H[bi][t][m] * Ud[k][m]
  for (int idx=tid; idx<9400; idx+=DEC_NT){
    int kq = idx/376;                 // k-quad 0..24
    int r  = idx - kq*376;            // 0..375
    int bi = r/94;
    int t  = r - 94*bi;
    const u32* hrow = (const u32*)sH + bi*4700 + t*50;
    const float* ud0 = Ud + (kq*4+0)*100;
    const float* ud1 = Ud + (kq*4+1)*100;
    const float* ud2 = Ud + (kq*4+2)*100;
    const float* ud3 = Ud + (kq*4+3)*100;
    float c0=0.f,c1=0.f,c2=0.f,c3=0.f;
    #pragma unroll 5
    for (int mq=0; mq<25; mq++){
      uint2 hp = *(const uint2*)(hrow + mq*2);
      float h0=bflo(hp.x), h1=bfhi(hp.x), h2=bflo(hp.y), h3=bfhi(hp.y);
      float4 u0 = *(const float4*)(ud0 + mq*4);
      float4 u1 = *(const float4*)(ud1 + mq*4);
      float4 u2 = *(const float4*)(ud2 + mq*4);
      float4 u3 = *(const float4*)(ud3 + mq*4);
      c0 += h0*u0.x + h1*u0.y + h2*u0.z + h3*u0.w;
      c1 += h0*u1.x + h1*u1.y + h2*u1.z + h3*u1.w;
      c2 += h0*u2.x + h1*u2.y + h2*u2.z + h3*u2.w;
      c3 += h0*u3.x + h1*u3.y + h2*u3.z + h3*u3.w;
    }
    u32* dst = (u32*)sHU + bi*4700 + t*50 + kq*2;
    dst[0] = packbf2(c0,c1);
    dst[1] = packbf2(c2,c3);
  }
  __syncthreads();

  // ---- load weights into registers AFTER the HU phase (lower peak VGPR pressure)
  __builtin_amdgcn_sched_barrier(0);
  const int mw = tid>>2, part = tid&3;
  u32 Wih[50]; u32 Whh[64]; u32 Wdf[32];
  float biasg;
  {
    const float2* wr = (const float2*)(wih + (size_t)tid*100);
    #pragma unroll
    for (int i=0;i<50;i++){ float2 v = wr[i]; Wih[i]=packh2(v.x,v.y); }
    const float2* hr = (const float2*)(whh + (size_t)tid*128);
    #pragma unroll
    for (int i=0;i<64;i++){ float2 v = hr[i]; Whh[i]=packh2(v.x,v.y); }
    biasg = bih[tid] + bhh[tid];
  }
  if (mw < 100){
    const float2* dr = (const float2*)(Wd + mw*256 + part*64);
    #pragma unroll
    for (int s=0;s<8;s++){
      int ii = (s+part)&7;           // rotated load to match rotated LDS reads
      #pragma unroll
      for (int k=0;k<4;k++){ float2 v = dr[ii*4+k]; Wdf[4*s+k]=packh2(v.x,v.y); }
    }
  }

  float s_reg = 0.f;                 // LSTM cell state, owned by this thread's (bi,p)

  for (int step=0; step<TM; step++){
    // P1: a[bi][m] = q[bi] . Wd[m]  (4 lanes per row; bank-rotated chunk order)
    if (mw < 100){
      #pragma unroll
      for (int bi=0;bi<NB;bi++){
        const u32* qb = (const u32*)sq2 + bi*128 + part*32;
        float a0=0.f, a1=0.f;
        #pragma unroll
        for (int s=0;s<8;s++){
          int ii = (s+part)&7;
          uint4 qv = *(const uint4*)(qb + ii*4);
          a0 = fdot2(Wdf[4*s+0], qv.x, a0);
          a1 = fdot2(Wdf[4*s+1], qv.y, a1);
          a0 = fdot2(Wdf[4*s+2], qv.z, a0);
          a1 = fdot2(Wdf[4*s+3], qv.w, a1);
        }
        float acc = a0+a1;
        acc += __shfl_xor(acc,1);
        acc += __shfl_xor(acc,2);
        if (part==0) sa[bi*100+mw]=acc;
      }
    }
    __syncthreads();
    // P2: scores[bi][t] = sum_m vd[m]*tanh(a[bi][m]+HU[bi][t][m]); one thread/row
    if (tid < 376){
      int bi = tid/94;
      int t  = tid - 94*bi;
      const u32* hu = (const u32*)sHU + bi*4700 + t*50;
      const float4* ap4 = (const float4*)(sa + bi*100);
      const float4* vp4 = (const float4*)svd;
      float acc=0.f;
      #pragma unroll
      for (int c=0;c<12;c++){
        uint4 h4 = ((const uint4*)hu)[c];
        float4 a0 = ap4[2*c], a1 = ap4[2*c+1];
        float4 v0 = vp4[2*c], v1 = vp4[2*c+1];
        acc += v0.x*tanh_f(a0.x + bflo(h4.x));
        acc += v0.y*tanh_f(a0.y + bfhi(h4.x));
        acc += v0.z*tanh_f(a0.z + bflo(h4.y));
        acc += v0.w*tanh_f(a0.w + bfhi(h4.y));
        acc += v1.x*tanh_f(a1.x + bflo(h4.z));
        acc += v1.y*tanh_f(a1.y + bfhi(h4.z));
        acc += v1.z*tanh_f(a1.z + bflo(h4.w));
        acc += v1.w*tanh_f(a1.w + bfhi(h4.w));
      }
      { // tail k=96..99
        uint2 ht = *(const uint2*)(hu + 48);
        float4 a = ap4[24]; float4 v = vp4[24];
        acc += v.x*tanh_f(a.x + bflo(ht.x));
        acc += v.y*tanh_f(a.y + bfhi(ht.x));
        acc += v.z*tanh_f(a.z + bflo(ht.y));
        acc += v.w*tanh_f(a.w + bfhi(ht.y));
      }
      sbeta[bi*96+t]=acc;
    }
    __syncthreads();
    // P3: softmax over t; wave per batch
    if (tid < 64*NB){
      int bi = tid>>6, lane = tid&63;
      float s0 = sbeta[bi*96+lane];
      float s1 = (lane<30)? sbeta[bi*96+64+lane] : -1e30f;
      float mx = fmaxf(s0,s1);
      #pragma unroll
      for (int o=32;o>=1;o>>=1) mx = fmaxf(mx, __shfl_xor(mx,o));
      float e0 = __expf(s0-mx);
      float e1 = (lane<30)? __expf(s1-mx) : 0.f;
      float sm = e0+e1;
      #pragma unroll
      for (int o=32;o>=1;o>>=1) sm += __shfl_xor(sm,o);
      float rs = fast_rcp(sm);
      sbeta[bi*96+lane] = e0*rs;
      if (lane<30) sbeta[bi*96+64+lane] = e1*rs;
    }
    __syncthreads();
    // P4: c[bi][m] = sum_t beta[bi][t]*H[bi][t][m]; thread=(bi, m-pair, t-half)
    if (tid < 400){
      int bi = tid/100;
      int r  = tid - 100*bi;
      int mp = r>>1, th = r&1;
      const float* bp = sbeta + bi*96 + th*47;
      const u32* hp = (const u32*)sH + bi*4700 + th*47*50 + mp;
      float a0=0.f, a1=0.f;
      #pragma unroll
      for (int i=0;i<47;i++){
        float be = bp[i];
        u32 h = hp[i*50];
        a0 += be*bflo(h); a1 += be*bfhi(h);
      }
      a0 += __shfl_xor(a0,1);
      a1 += __shfl_xor(a1,1);
      if (th==0){
        sc2[bi*52+mp] = packh2(a0,a1);
        if (step==TM-1){
          cLast[(size_t)(b0+bi)*100 + 2*mp]   = a0;
          cLast[(size_t)(b0+bi)*100 + 2*mp+1] = a1;
        }
      }
    }
    __syncthreads();
    // P5: gates[bi][tid] = bias + c.wih[tid] + d.whh[tid]
    #pragma unroll
    for (int bi=0;bi<NB;bi++){
      float a0 = biasg, a1 = 0.f;
      const uint4* cp = (const uint4*)(sc2 + bi*52);
      #pragma unroll
      for (int i=0;i<12;i++){
        uint4 cv = cp[i];
        a0 = fdot2(Wih[4*i+0], cv.x, a0);
        a1 = fdot2(Wih[4*i+1], cv.y, a1);
        a0 = fdot2(Wih[4*i+2], cv.z, a0);
        a1 = fdot2(Wih[4*i+3], cv.w, a1);
      }
      {
        const u32* ct = sc2 + bi*52 + 48;
        a0 = fdot2(Wih[48], ct[0], a0);
        a1 = fdot2(Wih[49], ct[1], a1);
      }
      const uint4* qp = (const uint4*)((const u32*)sq2 + bi*128);  // d part
      #pragma unroll
      for (int i=0;i<16;i++){
        uint4 qv = qp[i];
        a0 = fdot2(Whh[4*i+0], qv.x, a0);
        a1 = fdot2(Whh[4*i+1], qv.y, a1);
        a0 = fdot2(Whh[4*i+2], qv.z, a0);
        a1 = fdot2(Whh[4*i+3], qv.w, a1);
      }
      sg[bi*512+tid] = (_Float16)(a0+a1);
    }
    __syncthreads();
    // P6: LSTM pointwise update (all 512 threads: 4 bi x 128 p); s in register
    {
      int bi = tid>>7, p = tid&127;
      float ig = (float)sg[bi*512+p];
      float fg = (float)sg[bi*512+128+p];
      float gg = (float)sg[bi*512+256+p];
      float og = (float)sg[bi*512+384+p];
      float sn = sigmoid_f(fg)*s_reg + sigmoid_f(ig)*tanh_f(gg);
      float dn = sigmoid_f(og)*tanh_f(sn);
      s_reg = sn;
      sq2[bi*256+p]=(_Float16)dn;
      sq2[bi*256+128+p]=(_Float16)sn;
      if (step==TM-1) dT[(size_t)(b0+bi)*128+p]=dn;
    }
    __syncthreads();
  }
}

// ---------- kernel 3: skip GRU, 8 rows/block, 9 steps ----------
__global__ __launch_bounds__(256)
void gru_kernel(const u16* __restrict__ Hb, const float* __restrict__ wih,
                const float* __restrict__ whh, const float* __restrict__ bihp,
                const float* __restrict__ bhhp, float* __restrict__ hskip)
{
  __shared__ float sWih[96][101];
  __shared__ float sWhh[96][33];
  __shared__ float sxt[8][100];
  __shared__ float sh[8][33];
  const int tid = threadIdx.x;
  for (int i=tid;i<9600;i+=256){ sWih[i/100][i%100]=wih[i]; }
  for (int i=tid;i<3072;i+=256){ sWhh[i>>5][i&31]=whh[i]; }
  const int r = tid>>5, j = tid&31;
  const int rowg = blockIdx.x*8 + r;
  const int b = rowg/10, sk = rowg - b*10;
  const float b_r = bihp[j], b_z = bihp[32+j], b_n = bihp[64+j];
  const float hb_r = bhhp[j], hb_z = bhhp[32+j], hb_n = bhhp[64+j];
  sh[r][j]=0.f;
  float h = 0.f;
  __syncthreads();
  for (int pt=0; pt<9; pt++){
    for (int i=tid;i<800;i+=256){
      int rr=i/100, m=i-rr*100;
      int rg = blockIdx.x*8+rr; int bb=rg/10, ss=rg-bb*10;
      sxt[rr][m] = bf2f(Hb[(size_t)bb*9400 + (size_t)(4+pt*10+ss)*100 + m]);
    }
    __syncthreads();
    float gi_r=b_r, gi_z=b_z, gi_n=b_n, gh_r=hb_r, gh_z=hb_z, gh_n=hb_n;
    #pragma unroll 4
    for (int m=0;m<100;m++){
      float x = sxt[r][m];
      gi_r += sWih[j][m]*x; gi_z += sWih[32+j][m]*x; gi_n += sWih[64+j][m]*x;
    }
    #pragma unroll
    for (int k=0;k<32;k++){
      float hp = sh[r][k];
      gh_r += sWhh[j][k]*hp; gh_z += sWhh[32+j][k]*hp; gh_n += sWhh[64+j][k]*hp;
    }
    float rg_ = sigmoid_f(gi_r+gh_r);
    float z  = sigmoid_f(gi_z+gh_z);
    float n  = tanh_f(gi_n + rg_*gh_n);
    h = (1.f-z)*n + z*h;
    __syncthreads();
    sh[r][j]=h;
    __syncthreads();
  }
  hskip[(size_t)b*320 + sk*32 + j] = h;
}

// ---------- kernel 4: output MLP head, 32 batches/block, w1 tiled via LDS ----------
#define OUT_NB 32
#define OUT_LDS ((OUT_NB*552 + 8*552)*4)   // 88320 bytes

__global__ __launch_bounds__(256)
void out_kernel(const float* __restrict__ dT, const float* __restrict__ cLast,
                const float* __restrict__ hskip, const float* __restrict__ w1,
                const float* __restrict__ b1, const float* __restrict__ w2,
                const float* __restrict__ b2, float* __restrict__ outp)
{
  extern __shared__ float osm[];
  float* sf = osm;                 // [32][552]
  float* sw = osm + OUT_NB*552;    // [8][552]
  const int tid = threadIdx.x;
  const int b0 = blockIdx.x*OUT_NB;
  for (int i=tid;i<OUT_NB*548;i+=256){
    int bl = i/548, k = i - 548*bl; int b = b0+bl;
    float v;
    if (k<128) v = dT[(size_t)b*128+k];
    else if (k<228) v = cLast[(size_t)b*100+(k-128)];
    else v = hskip[(size_t)b*320+(k-228)];
    sf[bl*552+k]=v;
  }
  const int bl = tid>>3, j = tid&7;
  float outv = 0.f;
  for (int jt=0; jt<128; jt+=8){
    __syncthreads();
    for (int i=tid;i<8*548;i+=256){
      int rr=i/548, c=i-548*rr;
      sw[rr*552+c] = w1[(size_t)jt*548 + i];
    }
    __syncthreads();
    float acc = b1[jt+j];
    const float* fr = sf + bl*552;
    const float* wr = sw + j*552;
    #pragma unroll 4
    for (int k=0;k<548;k++) acc += fr[k]*wr[k];
    outv += fmaxf(acc,0.f)*w2[jt+j];
  }
  outv += __shfl_xor(outv,1);
  outv += __shfl_xor(outv,2);
  outv += __shfl_xor(outv,4);
  if (j==0) outp[b0+bl] = outv + b2[0];
}

// ---------- launcher ----------
extern "C" void kernel_launch(void* const* d_in, const int* in_sizes, int n_in,
                              void* d_out, int out_size, void* d_ws, size_t ws_size,
                              hipStream_t stream)
{
  const float* enc      = (const float*)d_in[0];
  const float* conv_w   = (const float*)d_in[1];
  const float* conv_b   = (const float*)d_in[2];
  const float* Wd       = (const float*)d_in[3];
  const float* Ud       = (const float*)d_in[4];
  const float* vd       = (const float*)d_in[5];
  const float* lstm_wih = (const float*)d_in[6];
  const float* lstm_whh = (const float*)d_in[7];
  const float* lstm_bih = (const float*)d_in[8];
  const float* lstm_bhh = (const float*)d_in[9];
  const float* gru_wih  = (const float*)d_in[10];
  const float* gru_whh  = (const float*)d_in[11];
  const float* gru_bih  = (const float*)d_in[12];
  const float* gru_bhh  = (const float*)d_in[13];
  const float* out1_w   = (const float*)d_in[14];
  const float* out1_b   = (const float*)d_in[15];
  const float* out2_w   = (const float*)d_in[16];
  const float* out2_b   = (const float*)d_in[17];

  char* ws = (char*)d_ws;
  u16*   Hb    = (u16*)ws;                         // 4096*9400*2 = 77,004,800 B
  float* dT    = (float*)(ws + 77004800);          // 4096*128*4  =  2,097,152 B
  float* cLast = (float*)(ws + 79101952);          // 4096*100*4  =  1,638,400 B
  float* hskip = (float*)(ws + 80740352);          // 4096*320*4  =  5,242,880 B

  conv_kernel<<<dim3(10,4096,1), 128, 0, stream>>>(enc, conv_w, conv_b, Hb);

  (void)hipFuncSetAttribute((const void*)decoder_kernel,
                            hipFuncAttributeMaxDynamicSharedMemorySize, DEC_LDS);
  decoder_kernel<<<4096/NB, DEC_NT, DEC_LDS, stream>>>(Hb, Wd, Ud, vd,
                                                       lstm_wih, lstm_whh, lstm_bih, lstm_bhh,
                                                       dT, cLast);

  gru_kernel<<<5120, 256, 0, stream>>>(Hb, gru_wih, gru_whh, gru_bih, gru_bhh, hskip);

  (void)hipFuncSetAttribute((const void*)out_kernel,
                            hipFuncAttributeMaxDynamicSharedMemorySize, OUT_LDS);
  out_kernel<<<4096/OUT_NB, 256, OUT_LDS, stream>>>(dT, cLast, hskip, out1_w, out1_b,
                                                    out2_w, out2_b, (float*)d_out);
}

// Round 4
// 7632.459 us; speedup vs baseline: 1.0926x; 1.0926x over previous
//
#include <hip/hip_runtime.h>

typedef unsigned int u32;
typedef unsigned short u16;
typedef _Float16 half2_t __attribute__((ext_vector_type(2)));

#define TM 94          // T_MOD
#define NB 4           // batches per decoder block
#define DEC_NT 1024

// ---------- helpers ----------
__device__ __forceinline__ float bf2f(u16 v){ return __builtin_bit_cast(float, ((u32)v)<<16); }
__device__ __forceinline__ float bflo(u32 v){ return __builtin_bit_cast(float, v<<16); }
__device__ __forceinline__ float bfhi(u32 v){ return __builtin_bit_cast(float, v & 0xffff0000u); }
__device__ __forceinline__ u32 f2bf_bits(float f){ u32 u=__builtin_bit_cast(u32,f); return (u + 0x7fffu + ((u>>16)&1u))>>16; }
__device__ __forceinline__ u32 packbf2(float a, float b){ return f2bf_bits(a) | (f2bf_bits(b)<<16); }
__device__ __forceinline__ u32 packh2(float a, float b){ half2_t h; h.x=(_Float16)a; h.y=(_Float16)b; return __builtin_bit_cast(u32,h); }
__device__ __forceinline__ float fdot2(u32 a, u32 b, float c){
  return __builtin_amdgcn_fdot2(__builtin_bit_cast(half2_t,a), __builtin_bit_cast(half2_t,b), c, false);
}
__device__ __forceinline__ float fast_rcp(float x){ return __builtin_amdgcn_rcpf(x); }
__device__ __forceinline__ float sigmoid_f(float x){ return fast_rcp(1.f + __expf(-x)); }
__device__ __forceinline__ float tanh_f(float x){ float e=__expf(2.f*x); return 1.f - 2.f*fast_rcp(e+1.f); }

// ---------- kernel 1: conv + relu -> H (bf16) ----------
__global__ __launch_bounds__(128)
void conv_kernel(const float* __restrict__ enc, const float* __restrict__ cw,
                 const float* __restrict__ cb, u16* __restrict__ Hb)
{
  __shared__ float sE[8100];
  const int tid = threadIdx.x;
  const int b = blockIdx.y;
  const int chunk = blockIdx.x;      // 10 chunks of 10 m's
  const float* ep = enc + (size_t)b*8100;
  for (int i=tid;i<8100;i+=128) sE[i]=ep[i];
  __syncthreads();
  if (tid >= TM) return;
  const int t = tid;
  const int mo = chunk*10;
  const float* wb = cw + mo*567;     // block-uniform -> scalar loads
  float acc[10];
  #pragma unroll
  for (int k=0;k<10;k++) acc[k]=cb[mo+k];
  const float* e = sE + t*81;
  #pragma unroll 3
  for (int j=0;j<567;j++){
    float ev = e[j];
    #pragma unroll
    for (int k=0;k<10;k++) acc[k] += ev*wb[k*567+j];
  }
  u32* out = (u32*)Hb + ((size_t)b*9400 + t*100 + mo)/2;
  #pragma unroll
  for (int k=0;k<5;k++) out[k] = packbf2(fmaxf(acc[2*k],0.f), fmaxf(acc[2*k+1],0.f));
}

// ---------- kernel 2: persistent decoder, NB=4, 1024 threads ----------
// LDS layout (bytes):
#define OFF_SHU 75200      // sHU [4][94][100] bf16
#define OFF_SQ2 150400     // q f16 [4][256] (d|s)
#define OFF_SC2 152448     // c f16-pairs u32 [4][52]
#define OFF_SVD 153280     // vd fp32 [100]
#define OFF_AB  153680     // union: {sa f32[4][100] @+0, sbeta f32[4][96] @+1600} / {sgA f16[4][512] @+0, sgB @+4096}
#define DEC_LDS 161872

// 1024-thread block => 16 waves MUST be co-resident => <=128 VGPRs mandatory.
// Worst-thread register demand restructured to ~100 so the 128 budget fits with
// no spills (rounds 1-3: 146-u32 weight arrays at 512 threads spilled ~50 MB).
__global__ __launch_bounds__(DEC_NT, 4)
__attribute__((amdgpu_waves_per_eu(4, 4)))
void decoder_kernel(const u16* __restrict__ Hb, const float* __restrict__ Wd,
                    const float* __restrict__ Ud, const float* __restrict__ vd,
                    const float* __restrict__ wih, const float* __restrict__ whh,
                    const float* __restrict__ bih, const float* __restrict__ bhh,
                    float* __restrict__ dT, float* __restrict__ cLast)
{
  extern __shared__ char smem[];
  u16*      sH   = (u16*)smem;                       // [4][94][100] bf16
  u16*      sHU  = (u16*)(smem + OFF_SHU);
  _Float16* sq2  = (_Float16*)(smem + OFF_SQ2);
  u32*      sc2  = (u32*)(smem + OFF_SC2);
  float*    svd  = (float*)(smem + OFF_SVD);
  float*    sa   = (float*)(smem + OFF_AB);          // live P1->P2
  float*    sbeta= (float*)(smem + OFF_AB + 1600);   // live P2->P4
  _Float16* sgA  = (_Float16*)(smem + OFF_AB);       // live P5->P6 (aliases sa/sbeta; barrier-separated)
  _Float16* sgB  = (_Float16*)(smem + OFF_AB + 4096);

  const int tid = threadIdx.x;
  const int b0 = blockIdx.x * NB;

  // stage H (4 batches): 4700 uint4
  {
    const uint4* src = (const uint4*)(Hb + (size_t)b0*9400);
    uint4* dst = (uint4*)sH;
    for (int i=tid;i<4700;i+=DEC_NT) dst[i]=src[i];
  }
  if (tid < 100) svd[tid] = vd[tid];
  {
    u32* q2 = (u32*)sq2;
    for (int i=tid;i<NB*128;i+=DEC_NT) q2[i]=0u;
  }
  __syncthreads();

  // HU[bi][t][k] = sum_m H[bi][t][m] * Ud[k][m]
  for (int idx=tid; idx<9400; idx+=DEC_NT){
    int kq = idx/376;                 // k-quad 0..24
    int r  = idx - kq*376;            // 0..375
    int bi = r/94;
    int t  = r - 94*bi;
    const u32* hrow = (const u32*)sH + bi*4700 + t*50;
    const float* ud0 = Ud + (kq*4+0)*100;
    const float* ud1 = Ud + (kq*4+1)*100;
    const float* ud2 = Ud + (kq*4+2)*100;
    const float* ud3 = Ud + (kq*4+3)*100;
    float c0=0.f,c1=0.f,c2=0.f,c3=0.f;
    #pragma unroll 5
    for (int mq=0; mq<25; mq++){
      uint2 hp = *(const uint2*)(hrow + mq*2);
      float h0=bflo(hp.x), h1=bfhi(hp.x), h2=bflo(hp.y), h3=bfhi(hp.y);
      float4 u0 = *(const float4*)(ud0 + mq*4);
      float4 u1 = *(const float4*)(ud1 + mq*4);
      float4 u2 = *(const float4*)(ud2 + mq*4);
      float4 u3 = *(const float4*)(ud3 + mq*4);
      c0 += h0*u0.x + h1*u0.y + h2*u0.z + h3*u0.w;
      c1 += h0*u1.x + h1*u1.y + h2*u1.z + h3*u1.w;
      c2 += h0*u2.x + h1*u2.y + h2*u2.z + h3*u2.w;
      c3 += h0*u3.x + h1*u3.y + h2*u3.z + h3*u3.w;
    }
    u32* dst = (u32*)sHU + bi*4700 + t*50 + kq*2;
    dst[0] = packbf2(c0,c1);
    dst[1] = packbf2(c2,c3);
  }
  __syncthreads();
  __builtin_amdgcn_sched_barrier(0);

  // ---- register weights, K-split across wave halves ----
  const int half = tid >> 9;         // waves 0-7: lower, 8-15: upper
  const int g    = tid & 511;        // gate row
  u32 WA[58];
  float biasg = 0.f;
  if (half == 0){
    const float2* wr = (const float2*)(wih + (size_t)g*100);
    #pragma unroll
    for (int i=0;i<50;i++){ float2 v = wr[i]; WA[i]=packh2(v.x,v.y); }
    const float2* hr = (const float2*)(whh + (size_t)g*128);
    #pragma unroll
    for (int i=0;i<8;i++){ float2 v = hr[i]; WA[50+i]=packh2(v.x,v.y); }
    biasg = bih[g] + bhh[g];
  } else {
    const float2* hr = (const float2*)(whh + (size_t)g*128 + 16);
    #pragma unroll
    for (int i=0;i<56;i++){ float2 v = hr[i]; WA[i]=packh2(v.x,v.y); }
  }
  // Wd fragments: 8 lanes per row, 16 u32 each, chunk-rotated by lane for LDS banks
  const int mw = tid>>3, part = tid&7;
  u32 Wdf[16];
  if (mw < 100){
    const float* wd = Wd + mw*256 + part*32;
    #pragma unroll
    for (int i=0;i<4;i++){
      int ii = (i+part)&3;
      #pragma unroll
      for (int k=0;k<4;k++){
        Wdf[4*i+k] = packh2(wd[ii*8+2*k], wd[ii*8+2*k+1]);
      }
    }
  }

  float s_reg = 0.f;                 // LSTM cell state (threads tid<512)

  for (int step=0; step<TM; step++){
    // P1: a[bi][m] = q[bi] . Wd[m]  (8 lanes per row)
    if (mw < 100){
      #pragma unroll 1
      for (int bi=0;bi<NB;bi++){
        const u32* qb = (const u32*)sq2 + bi*128 + part*16;
        float a0=0.f, a1=0.f;
        #pragma unroll
        for (int i=0;i<4;i++){
          int ii = (i+part)&3;
          uint4 qv = *(const uint4*)(qb + ii*4);
          a0 = fdot2(Wdf[4*i+0], qv.x, a0);
          a1 = fdot2(Wdf[4*i+1], qv.y, a1);
          a0 = fdot2(Wdf[4*i+2], qv.z, a0);
          a1 = fdot2(Wdf[4*i+3], qv.w, a1);
        }
        float acc = a0+a1;
        acc += __shfl_xor(acc,1);
        acc += __shfl_xor(acc,2);
        acc += __shfl_xor(acc,4);
        if (part==0) sa[bi*100+mw]=acc;
      }
    }
    __syncthreads();
    // P2: scores[bi][t] = sum_m vd[m]*tanh(a[bi][m]+HU[bi][t][m]); 2 threads/row
    if (tid < 752){
      int row = tid>>1, th = tid&1;
      int bi = row/94;
      int t  = row - 94*bi;
      const uint4* hu4 = (const uint4*)((const u32*)sHU + bi*4700 + t*50 + th*24);
      const float4* ap = (const float4*)(sa + bi*100) + th*12;
      const float4* vp = (const float4*)svd + th*12;
      float acc=0.f;
      #pragma unroll
      for (int c=0;c<6;c++){
        uint4 h4 = hu4[c];
        float4 a0 = ap[2*c], a1 = ap[2*c+1];
        float4 v0 = vp[2*c], v1 = vp[2*c+1];
        acc += v0.x*tanh_f(a0.x + bflo(h4.x));
        acc += v0.y*tanh_f(a0.y + bfhi(h4.x));
        acc += v0.z*tanh_f(a0.z + bflo(h4.y));
        acc += v0.w*tanh_f(a0.w + bfhi(h4.y));
        acc += v1.x*tanh_f(a1.x + bflo(h4.z));
        acc += v1.y*tanh_f(a1.y + bfhi(h4.z));
        acc += v1.z*tanh_f(a1.z + bflo(h4.w));
        acc += v1.w*tanh_f(a1.w + bfhi(h4.w));
      }
      if (th){ // tail m=96..99 (u32 rel idx 24,25)
        uint2 ht = *(const uint2*)((const u32*)hu4 + 24);
        float4 a = ap[12]; float4 v = vp[12];
        acc += v.x*tanh_f(a.x + bflo(ht.x));
        acc += v.y*tanh_f(a.y + bfhi(ht.x));
        acc += v.z*tanh_f(a.z + bflo(ht.y));
        acc += v.w*tanh_f(a.w + bfhi(ht.y));
      }
      acc += __shfl_xor(acc,1);
      if (!th) sbeta[bi*96+t]=acc;
    }
    __syncthreads();
    // P3: softmax over t; one wave per batch
    if (tid < 64*NB){
      int bi = tid>>6, lane = tid&63;
      float s0 = sbeta[bi*96+lane];
      float s1 = (lane<30)? sbeta[bi*96+64+lane] : -1e30f;
      float mx = fmaxf(s0,s1);
      #pragma unroll
      for (int o=32;o>=1;o>>=1) mx = fmaxf(mx, __shfl_xor(mx,o));
      float e0 = __expf(s0-mx);
      float e1 = (lane<30)? __expf(s1-mx) : 0.f;
      float sm = e0+e1;
      #pragma unroll
      for (int o=32;o>=1;o>>=1) sm += __shfl_xor(sm,o);
      float rs = fast_rcp(sm);
      sbeta[bi*96+lane] = e0*rs;
      if (lane<30) sbeta[bi*96+64+lane] = e1*rs;
    }
    __syncthreads();
    // P4: c[bi][m] = sum_t beta[bi][t]*H[bi][t][m]; 4 threads per (bi,m-pair)
    if (tid < 800){
      int bi = tid/200;
      int r  = tid - 200*bi;
      int mp = r>>2, th = r&3;
      int tstart = (th<2) ? th*24 : 48+(th-2)*23;
      const float* bp = sbeta + bi*96 + tstart;
      const u32* hp = (const u32*)sH + bi*4700 + tstart*50 + mp;
      float a0=0.f, a1=0.f;
      #pragma unroll
      for (int i=0;i<23;i++){
        float be = bp[i];
        u32 h = hp[i*50];
        a0 += be*bflo(h); a1 += be*bfhi(h);
      }
      if (th<2){
        float be = bp[23]; u32 h = hp[23*50];
        a0 += be*bflo(h); a1 += be*bfhi(h);
      }
      a0 += __shfl_xor(a0,1); a1 += __shfl_xor(a1,1);
      a0 += __shfl_xor(a0,2); a1 += __shfl_xor(a1,2);
      if (th==0){
        sc2[bi*52+mp] = packh2(a0,a1);
        if (step==TM-1){
          cLast[(size_t)(b0+bi)*100 + 2*mp]   = a0;
          cLast[(size_t)(b0+bi)*100 + 2*mp+1] = a1;
        }
      }
    }
    __syncthreads();
    // P5: gate partials, K-split. lower: bias + Wih.c + Whh[0:16cols].d ; upper: Whh[16:128cols].d
    if (half == 0){
      #pragma unroll 1
      for (int bi=0;bi<NB;bi++){
        float a0 = biasg, a1 = 0.f;
        const uint4* cp = (const uint4*)(sc2 + bi*52);
        #pragma unroll
        for (int i=0;i<12;i++){
          uint4 cv = cp[i];
          a0 = fdot2(WA[4*i+0], cv.x, a0);
          a1 = fdot2(WA[4*i+1], cv.y, a1);
          a0 = fdot2(WA[4*i+2], cv.z, a0);
          a1 = fdot2(WA[4*i+3], cv.w, a1);
        }
        {
          const u32* ct = sc2 + bi*52 + 48;
          a0 = fdot2(WA[48], ct[0], a0);
          a1 = fdot2(WA[49], ct[1], a1);
        }
        const uint4* qp = (const uint4*)((const u32*)sq2 + bi*128);
        #pragma unroll
        for (int i=0;i<2;i++){
          uint4 qv = qp[i];
          a0 = fdot2(WA[50+4*i+0], qv.x, a0);
          a1 = fdot2(WA[50+4*i+1], qv.y, a1);
          a0 = fdot2(WA[50+4*i+2], qv.z, a0);
          a1 = fdot2(WA[50+4*i+3], qv.w, a1);
        }
        sgA[bi*512+g] = (_Float16)(a0+a1);
      }
    } else {
      #pragma unroll 1
      for (int bi=0;bi<NB;bi++){
        float a0 = 0.f, a1 = 0.f;
        const uint4* qp = (const uint4*)((const u32*)sq2 + bi*128);
        #pragma unroll
        for (int i=0;i<14;i++){
          uint4 qv = qp[2+i];
          a0 = fdot2(WA[4*i+0], qv.x, a0);
          a1 = fdot2(WA[4*i+1], qv.y, a1);
          a0 = fdot2(WA[4*i+2], qv.z, a0);
          a1 = fdot2(WA[4*i+3], qv.w, a1);
        }
        sgB[bi*512+g] = (_Float16)(a0+a1);
      }
    }
    __syncthreads();
    // P6: LSTM pointwise update (tid<512: 4 bi x 128 p); s in register
    if (tid < 512){
      int bi = tid>>7, p = tid&127;
      float ig = (float)sgA[bi*512+p]       + (float)sgB[bi*512+p];
      float fg = (float)sgA[bi*512+128+p]   + (float)sgB[bi*512+128+p];
      float gg = (float)sgA[bi*512+256+p]   + (float)sgB[bi*512+256+p];
      float og = (float)sgA[bi*512+384+p]   + (float)sgB[bi*512+384+p];
      float sn = sigmoid_f(fg)*s_reg + sigmoid_f(ig)*tanh_f(gg);
      float dn = sigmoid_f(og)*tanh_f(sn);
      s_reg = sn;
      sq2[bi*256+p]=(_Float16)dn;
      sq2[bi*256+128+p]=(_Float16)sn;
      if (step==TM-1) dT[(size_t)(b0+bi)*128+p]=dn;
    }
    __syncthreads();
  }
}

// ---------- kernel 3: skip GRU, 8 rows/block, 9 steps ----------
__global__ __launch_bounds__(256)
void gru_kernel(const u16* __restrict__ Hb, const float* __restrict__ wih,
                const float* __restrict__ whh, const float* __restrict__ bihp,
                const float* __restrict__ bhhp, float* __restrict__ hskip)
{
  __shared__ float sWih[96][101];
  __shared__ float sWhh[96][33];
  __shared__ float sxt[8][100];
  __shared__ float sh[8][33];
  const int tid = threadIdx.x;
  for (int i=tid;i<9600;i+=256){ sWih[i/100][i%100]=wih[i]; }
  for (int i=tid;i<3072;i+=256){ sWhh[i>>5][i&31]=whh[i]; }
  const int r = tid>>5, j = tid&31;
  const int rowg = blockIdx.x*8 + r;
  const int b = rowg/10, sk = rowg - b*10;
  const float b_r = bihp[j], b_z = bihp[32+j], b_n = bihp[64+j];
  const float hb_r = bhhp[j], hb_z = bhhp[32+j], hb_n = bhhp[64+j];
  sh[r][j]=0.f;
  float h = 0.f;
  __syncthreads();
  for (int pt=0; pt<9; pt++){
    for (int i=tid;i<800;i+=256){
      int rr=i/100, m=i-rr*100;
      int rg = blockIdx.x*8+rr; int bb=rg/10, ss=rg-bb*10;
      sxt[rr][m] = bf2f(Hb[(size_t)bb*9400 + (size_t)(4+pt*10+ss)*100 + m]);
    }
    __syncthreads();
    float gi_r=b_r, gi_z=b_z, gi_n=b_n, gh_r=hb_r, gh_z=hb_z, gh_n=hb_n;
    #pragma unroll 4
    for (int m=0;m<100;m++){
      float x = sxt[r][m];
      gi_r += sWih[j][m]*x; gi_z += sWih[32+j][m]*x; gi_n += sWih[64+j][m]*x;
    }
    #pragma unroll
    for (int k=0;k<32;k++){
      float hp = sh[r][k];
      gh_r += sWhh[j][k]*hp; gh_z += sWhh[32+j][k]*hp; gh_n += sWhh[64+j][k]*hp;
    }
    float rg_ = sigmoid_f(gi_r+gh_r);
    float z  = sigmoid_f(gi_z+gh_z);
    float n  = tanh_f(gi_n + rg_*gh_n);
    h = (1.f-z)*n + z*h;
    __syncthreads();
    sh[r][j]=h;
    __syncthreads();
  }
  hskip[(size_t)b*320 + sk*32 + j] = h;
}

// ---------- kernel 4: output MLP head, 32 batches/block, w1 tiled via LDS ----------
#define OUT_NB 32
#define OUT_LDS ((OUT_NB*552 + 8*552)*4)   // 88320 bytes

__global__ __launch_bounds__(256)
void out_kernel(const float* __restrict__ dT, const float* __restrict__ cLast,
                const float* __restrict__ hskip, const float* __restrict__ w1,
                const float* __restrict__ b1, const float* __restrict__ w2,
                const float* __restrict__ b2, float* __restrict__ outp)
{
  extern __shared__ float osm[];
  float* sf = osm;                 // [32][552]
  float* sw = osm + OUT_NB*552;    // [8][552]
  const int tid = threadIdx.x;
  const int b0 = blockIdx.x*OUT_NB;
  for (int i=tid;i<OUT_NB*548;i+=256){
    int bl = i/548, k = i - 548*bl; int b = b0+bl;
    float v;
    if (k<128) v = dT[(size_t)b*128+k];
    else if (k<228) v = cLast[(size_t)b*100+(k-128)];
    else v = hskip[(size_t)b*320+(k-228)];
    sf[bl*552+k]=v;
  }
  const int bl = tid>>3, j = tid&7;
  float outv = 0.f;
  for (int jt=0; jt<128; jt+=8){
    __syncthreads();
    for (int i=tid;i<8*548;i+=256){
      int rr=i/548, c=i-548*rr;
      sw[rr*552+c] = w1[(size_t)jt*548 + i];
    }
    __syncthreads();
    float acc = b1[jt+j];
    const float* fr = sf + bl*552;
    const float* wr = sw + j*552;
    #pragma unroll 4
    for (int k=0;k<548;k++) acc += fr[k]*wr[k];
    outv += fmaxf(acc,0.f)*w2[jt+j];
  }
  outv += __shfl_xor(outv,1);
  outv += __shfl_xor(outv,2);
  outv += __shfl_xor(outv,4);
  if (j==0) outp[b0+bl] = outv + b2[0];
}

// ---------- launcher ----------
extern "C" void kernel_launch(void* const* d_in, const int* in_sizes, int n_in,
                              void* d_out, int out_size, void* d_ws, size_t ws_size,
                              hipStream_t stream)
{
  const float* enc      = (const float*)d_in[0];
  const float* conv_w   = (const float*)d_in[1];
  const float* conv_b   = (const float*)d_in[2];
  const float* Wd       = (const float*)d_in[3];
  const float* Ud       = (const float*)d_in[4];
  const float* vd       = (const float*)d_in[5];
  const float* lstm_wih = (const float*)d_in[6];
  const float* lstm_whh = (const float*)d_in[7];
  const float* lstm_bih = (const float*)d_in[8];
  const float* lstm_bhh = (const float*)d_in[9];
  const float* gru_wih  = (const float*)d_in[10];
  const float* gru_whh  = (const float*)d_in[11];
  const float* gru_bih  = (const float*)d_in[12];
  const float* gru_bhh  = (const float*)d_in[13];
  const float* out1_w   = (const float*)d_in[14];
  const float* out1_b   = (const float*)d_in[15];
  const float* out2_w   = (const float*)d_in[16];
  const float* out2_b   = (const float*)d_in[17];

  char* ws = (char*)d_ws;
  u16*   Hb    = (u16*)ws;                         // 4096*9400*2 = 77,004,800 B
  float* dT    = (float*)(ws + 77004800);          // 4096*128*4  =  2,097,152 B
  float* cLast = (float*)(ws + 79101952);          // 4096*100*4  =  1,638,400 B
  float* hskip = (float*)(ws + 80740352);          // 4096*320*4  =  5,242,880 B

  conv_kernel<<<dim3(10,4096,1), 128, 0, stream>>>(enc, conv_w, conv_b, Hb);

  (void)hipFuncSetAttribute((const void*)decoder_kernel,
                            hipFuncAttributeMaxDynamicSharedMemorySize, DEC_LDS);
  decoder_kernel<<<4096/NB, DEC_NT, DEC_LDS, stream>>>(Hb, Wd, Ud, vd,
                                                       lstm_wih, lstm_whh, lstm_bih, lstm_bhh,
                                                       dT, cLast);

  gru_kernel<<<5120, 256, 0, stream>>>(Hb, gru_wih, gru_whh, gru_bih, gru_bhh, hskip);

  (void)hipFuncSetAttribute((const void*)out_kernel,
                            hipFuncAttributeMaxDynamicSharedMemorySize, OUT_LDS);
  out_kernel<<<4096/OUT_NB, 256, OUT_LDS, stream>>>(dT, cLast, hskip, out1_w, out1_b,
                                                    out2_w, out2_b, (float*)d_out);
}

// Round 5
// 7544.016 us; speedup vs baseline: 1.1055x; 1.0117x over previous
//
#include <hip/hip_runtime.h>

typedef unsigned int u32;
typedef unsigned short u16;
typedef _Float16 half2_t __attribute__((ext_vector_type(2)));

#define TM 94          // T_MOD
#define NB 4           // batches per decoder block
#define DEC_NT 1024

// ---------- helpers ----------
__device__ __forceinline__ float bf2f(u16 v){ return __builtin_bit_cast(float, ((u32)v)<<16); }
__device__ __forceinline__ float bflo(u32 v){ return __builtin_bit_cast(float, v<<16); }
__device__ __forceinline__ float bfhi(u32 v){ return __builtin_bit_cast(float, v & 0xffff0000u); }
__device__ __forceinline__ u32 f2bf_bits(float f){ u32 u=__builtin_bit_cast(u32,f); return (u + 0x7fffu + ((u>>16)&1u))>>16; }
__device__ __forceinline__ u32 packbf2(float a, float b){ return f2bf_bits(a) | (f2bf_bits(b)<<16); }
__device__ __forceinline__ u32 packh2(float a, float b){ half2_t h; h.x=(_Float16)a; h.y=(_Float16)b; return __builtin_bit_cast(u32,h); }
__device__ __forceinline__ float fdot2(u32 a, u32 b, float c){
  return __builtin_amdgcn_fdot2(__builtin_bit_cast(half2_t,a), __builtin_bit_cast(half2_t,b), c, false);
}
__device__ __forceinline__ float fast_rcp(float x){ return __builtin_amdgcn_rcpf(x); }
__device__ __forceinline__ float sigmoid_f(float x){ return fast_rcp(1.f + __expf(-x)); }
__device__ __forceinline__ float tanh_f(float x){ float e=__expf(2.f*x); return 1.f - 2.f*fast_rcp(e+1.f); }

// ---------- kernel 0: pack LSTM weights to f16, K-transposed for coalesced streaming ----------
// WgT[j][t] (uint4): thread t = h*512+g; h=0: wih row g (u32 k-idx u=4j+s, u<50), h=1: whh row g (u<64)
__global__ __launch_bounds__(256)
void prep_kernel(const float* __restrict__ wih, const float* __restrict__ whh,
                 uint4* __restrict__ WgT)
{
  int idx = blockIdx.x*256 + threadIdx.x;   // 0..16383
  int t = idx & 1023;
  int j = idx >> 10;
  int h = t >> 9, g = t & 511;
  u32 r[4];
  #pragma unroll
  for (int s=0;s<4;s++){
    int u = 4*j + s;
    u32 v = 0u;
    if (h==0){ if (u < 50) v = packh2(wih[g*100+2*u], wih[g*100+2*u+1]); }
    else     { if (u < 64) v = packh2(whh[g*128+2*u], whh[g*128+2*u+1]); }
    r[s]=v;
  }
  WgT[idx] = make_uint4(r[0],r[1],r[2],r[3]);
}

// ---------- kernel 1: conv + relu -> H (bf16) ----------
__global__ __launch_bounds__(128)
void conv_kernel(const float* __restrict__ enc, const float* __restrict__ cw,
                 const float* __restrict__ cb, u16* __restrict__ Hb)
{
  __shared__ float sE[8100];
  const int tid = threadIdx.x;
  const int b = blockIdx.y;
  const int chunk = blockIdx.x;      // 10 chunks of 10 m's
  const float* ep = enc + (size_t)b*8100;
  for (int i=tid;i<8100;i+=128) sE[i]=ep[i];
  __syncthreads();
  if (tid >= TM) return;
  const int t = tid;
  const int mo = chunk*10;
  const float* wb = cw + mo*567;     // block-uniform -> scalar loads
  float acc[10];
  #pragma unroll
  for (int k=0;k<10;k++) acc[k]=cb[mo+k];
  const float* e = sE + t*81;
  #pragma unroll 3
  for (int j=0;j<567;j++){
    float ev = e[j];
    #pragma unroll
    for (int k=0;k<10;k++) acc[k] += ev*wb[k*567+j];
  }
  u32* out = (u32*)Hb + ((size_t)b*9400 + t*100 + mo)/2;
  #pragma unroll
  for (int k=0;k<5;k++) out[k] = packbf2(fmaxf(acc[2*k],0.f), fmaxf(acc[2*k+1],0.f));
}

// ---------- kernel 2: persistent decoder, NB=4, 1024 threads ----------
// LDS layout (bytes):
#define OFF_SHU 75200      // sHU [4][94][50] u32 bf16-pairs
#define OFF_SQ  150400     // sq16 u32[4][128]: q=[d|s] f16 pairs (P1)
#define OFF_SZ  152448     // sz  u32[4][128]: z=[c(50)+pad(14)|d(64)] f16 pairs (P5)
#define OFF_SVD 154496     // vd fp32 [100]
#define OFF_AB  154896     // union: {sa f32[4][100]@0, sbeta f32[4][96]@1600} / {sgA f16[4][512]@0, sgB @4096}
#define DEC_LDS 163088

// No waves_per_eu attr (rounds 2-4: allocator targets 2x declared occupancy and
// spills). Worst-thread demand is now ~70 VGPRs, safe under any budget >=64.
__global__ __launch_bounds__(DEC_NT, 2)
void decoder_kernel(const u16* __restrict__ Hb, const float* __restrict__ Wd,
                    const float* __restrict__ Ud, const float* __restrict__ vd,
                    const uint4* __restrict__ WgT,
                    const float* __restrict__ bih, const float* __restrict__ bhh,
                    float* __restrict__ dT, float* __restrict__ cLast)
{
  extern __shared__ char smem[];
  u16*      sH   = (u16*)smem;                       // [4][94][100] bf16
  u16*      sHU  = (u16*)(smem + OFF_SHU);
  u32*      sq32 = (u32*)(smem + OFF_SQ);
  _Float16* sq16 = (_Float16*)(smem + OFF_SQ);
  u32*      sz32 = (u32*)(smem + OFF_SZ);
  _Float16* sz16 = (_Float16*)(smem + OFF_SZ);
  float*    svd  = (float*)(smem + OFF_SVD);
  float*    sa   = (float*)(smem + OFF_AB);          // live P1->P2
  float*    sbeta= (float*)(smem + OFF_AB + 1600);   // live P2->P4
  _Float16* sgA  = (_Float16*)(smem + OFF_AB);       // live P5->P6 (aliases sa/sbeta; barrier-separated)
  _Float16* sgB  = (_Float16*)(smem + OFF_AB + 4096);

  const int tid = threadIdx.x;
  const int b0 = blockIdx.x * NB;

  // stage H (4 batches): 4700 uint4
  {
    const uint4* src = (const uint4*)(Hb + (size_t)b0*9400);
    uint4* dst = (uint4*)sH;
    for (int i=tid;i<4700;i+=DEC_NT) dst[i]=src[i];
  }
  if (tid < 100) svd[tid] = vd[tid];
  for (int i=tid;i<NB*128;i+=DEC_NT){ sq32[i]=0u; sz32[i]=0u; }
  __syncthreads();

  // HU[bi][t][k] = sum_m H[bi][t][m] * Ud[k][m]
  for (int idx=tid; idx<9400; idx+=DEC_NT){
    int kq = idx/376;                 // k-quad 0..24
    int r  = idx - kq*376;            // 0..375
    int bi = r/94;
    int t  = r - 94*bi;
    const u32* hrow = (const u32*)sH + bi*4700 + t*50;
    const float* ud0 = Ud + (kq*4+0)*100;
    const float* ud1 = Ud + (kq*4+1)*100;
    const float* ud2 = Ud + (kq*4+2)*100;
    const float* ud3 = Ud + (kq*4+3)*100;
    float c0=0.f,c1=0.f,c2=0.f,c3=0.f;
    #pragma unroll 5
    for (int mq=0; mq<25; mq++){
      uint2 hp = *(const uint2*)(hrow + mq*2);
      float h0=bflo(hp.x), h1=bfhi(hp.x), h2=bflo(hp.y), h3=bfhi(hp.y);
      float4 u0 = *(const float4*)(ud0 + mq*4);
      float4 u1 = *(const float4*)(ud1 + mq*4);
      float4 u2 = *(const float4*)(ud2 + mq*4);
      float4 u3 = *(const float4*)(ud3 + mq*4);
      c0 += h0*u0.x + h1*u0.y + h2*u0.z + h3*u0.w;
      c1 += h0*u1.x + h1*u1.y + h2*u1.z + h3*u1.w;
      c2 += h0*u2.x + h1*u2.y + h2*u2.z + h3*u2.w;
      c3 += h0*u3.x + h1*u3.y + h2*u3.z + h3*u3.w;
    }
    u32* dst = (u32*)sHU + bi*4700 + t*50 + kq*2;
    dst[0] = packbf2(c0,c1);
    dst[1] = packbf2(c2,c3);
  }
  __syncthreads();

  // Wd fragments: 8 lanes per row, 16 u32 each, chunk-rotated by lane for LDS banks
  const int mw = tid>>3, part = tid&7;
  u32 Wdf[16];
  if (mw < 100){
    const float* wd = Wd + mw*256 + part*32;
    #pragma unroll
    for (int i=0;i<4;i++){
      int ii = (i+part)&3;
      #pragma unroll
      for (int k=0;k<4;k++){
        Wdf[4*i+k] = packh2(wd[ii*8+2*k], wd[ii*8+2*k+1]);
      }
    }
  }
  // gate bias (h==0 threads own the bias)
  const int gh = tid >> 9, gg = tid & 511;
  const float biasg = (gh==0) ? (bih[gg] + bhh[gg]) : 0.f;
  const uint4* wgp = WgT + tid;
  const int jmax = gh ? 16 : 13;

  float s_reg = 0.f;                 // LSTM cell state (threads tid<512)

  #pragma unroll 1
  for (int step=0; step<TM; step++){
    // P1: a[bi][m] = q[bi] . Wd[m]  (8 lanes per row)
    if (mw < 100){
      #pragma unroll 1
      for (int bi=0;bi<NB;bi++){
        const u32* qb = sq32 + bi*128 + part*16;
        float a0=0.f, a1=0.f;
        #pragma unroll
        for (int i=0;i<4;i++){
          int ii = (i+part)&3;
          uint4 qv = *(const uint4*)(qb + ii*4);
          a0 = fdot2(Wdf[4*i+0], qv.x, a0);
          a1 = fdot2(Wdf[4*i+1], qv.y, a1);
          a0 = fdot2(Wdf[4*i+2], qv.z, a0);
          a1 = fdot2(Wdf[4*i+3], qv.w, a1);
        }
        float acc = a0+a1;
        acc += __shfl_xor(acc,1);
        acc += __shfl_xor(acc,2);
        acc += __shfl_xor(acc,4);
        if (part==0) sa[bi*100+mw]=acc;
      }
    }
    __syncthreads();
    // P2: scores[bi][t] = sum_m vd[m]*tanh(a[bi][m]+HU[bi][t][m]); 2 threads/row
    if (tid < 752){
      int row = tid>>1, th = tid&1;
      int bi = row/94;
      int t  = row - 94*bi;
      const uint4* hu4 = (const uint4*)((const u32*)sHU + bi*4700 + t*50 + th*24);
      const float4* ap = (const float4*)(sa + bi*100) + th*12;
      const float4* vp = (const float4*)svd + th*12;
      float acc=0.f;
      #pragma unroll
      for (int c=0;c<6;c++){
        uint4 h4 = hu4[c];
        float4 a0 = ap[2*c], a1 = ap[2*c+1];
        float4 v0 = vp[2*c], v1 = vp[2*c+1];
        acc += v0.x*tanh_f(a0.x + bflo(h4.x));
        acc += v0.y*tanh_f(a0.y + bfhi(h4.x));
        acc += v0.z*tanh_f(a0.z + bflo(h4.y));
        acc += v0.w*tanh_f(a0.w + bfhi(h4.y));
        acc += v1.x*tanh_f(a1.x + bflo(h4.z));
        acc += v1.y*tanh_f(a1.y + bfhi(h4.z));
        acc += v1.z*tanh_f(a1.z + bflo(h4.w));
        acc += v1.w*tanh_f(a1.w + bfhi(h4.w));
      }
      if (th){ // tail m=96..99
        uint2 ht = *(const uint2*)((const u32*)hu4 + 24);
        float4 a = ap[12]; float4 v = vp[12];
        acc += v.x*tanh_f(a.x + bflo(ht.x));
        acc += v.y*tanh_f(a.y + bfhi(ht.x));
        acc += v.z*tanh_f(a.z + bflo(ht.y));
        acc += v.w*tanh_f(a.w + bfhi(ht.y));
      }
      acc += __shfl_xor(acc,1);
      if (!th) sbeta[bi*96+t]=acc;
    }
    __syncthreads();
    // P3: softmax over t; one wave per batch
    if (tid < 64*NB){
      int bi = tid>>6, lane = tid&63;
      float s0 = sbeta[bi*96+lane];
      float s1 = (lane<30)? sbeta[bi*96+64+lane] : -1e30f;
      float mx = fmaxf(s0,s1);
      #pragma unroll
      for (int o=32;o>=1;o>>=1) mx = fmaxf(mx, __shfl_xor(mx,o));
      float e0 = __expf(s0-mx);
      float e1 = (lane<30)? __expf(s1-mx) : 0.f;
      float sm = e0+e1;
      #pragma unroll
      for (int o=32;o>=1;o>>=1) sm += __shfl_xor(sm,o);
      float rs = fast_rcp(sm);
      sbeta[bi*96+lane] = e0*rs;
      if (lane<30) sbeta[bi*96+64+lane] = e1*rs;
    }
    __syncthreads();
    // P4: c[bi][m] = sum_t beta[bi][t]*H[bi][t][m]; 4 threads per (bi,m-pair)
    if (tid < 800){
      int bi = tid/200;
      int r  = tid - 200*bi;
      int mp = r>>2, th = r&3;
      int tstart = (th<2) ? th*24 : 48+(th-2)*23;
      const float* bp = sbeta + bi*96 + tstart;
      const u32* hp = (const u32*)sH + bi*4700 + tstart*50 + mp;
      float a0=0.f, a1=0.f;
      #pragma unroll
      for (int i=0;i<23;i++){
        float be = bp[i];
        u32 h = hp[i*50];
        a0 += be*bflo(h); a1 += be*bfhi(h);
      }
      if (th<2){
        float be = bp[23]; u32 h = hp[23*50];
        a0 += be*bflo(h); a1 += be*bfhi(h);
      }
      a0 += __shfl_xor(a0,1); a1 += __shfl_xor(a1,1);
      a0 += __shfl_xor(a0,2); a1 += __shfl_xor(a1,2);
      if (th==0){
        sz32[bi*128+mp] = packh2(a0,a1);
        if (step==TM-1){
          cLast[(size_t)(b0+bi)*100 + 2*mp]   = a0;
          cLast[(size_t)(b0+bi)*100 + 2*mp+1] = a1;
        }
      }
    }
    __syncthreads();
    // P5: gate partials via streamed L2-resident weights, 2-deep prefetch.
    // z reads are wave-uniform (gh uniform per wave) -> LDS broadcast, conflict-free.
    {
      float acc0 = biasg, acc1 = biasg, acc2 = biasg, acc3 = biasg;
      uint4 w0 = wgp[0], w1 = wgp[1024];
      const u32* zb = sz32 + gh*64;
      #pragma unroll 1
      for (int j=0;j<jmax;j++){
        uint4 wc = w0; w0 = w1;
        int jn = (j+2<16)? j+2 : 15;
        w1 = wgp[jn*1024];
        const u32* z0 = zb + 4*j;
        uint4 zv0 = *(const uint4*)(z0);
        uint4 zv1 = *(const uint4*)(z0+128);
        uint4 zv2 = *(const uint4*)(z0+256);
        uint4 zv3 = *(const uint4*)(z0+384);
        acc0 = fdot2(wc.x, zv0.x, acc0); acc0 = fdot2(wc.y, zv0.y, acc0);
        acc0 = fdot2(wc.z, zv0.z, acc0); acc0 = fdot2(wc.w, zv0.w, acc0);
        acc1 = fdot2(wc.x, zv1.x, acc1); acc1 = fdot2(wc.y, zv1.y, acc1);
        acc1 = fdot2(wc.z, zv1.z, acc1); acc1 = fdot2(wc.w, zv1.w, acc1);
        acc2 = fdot2(wc.x, zv2.x, acc2); acc2 = fdot2(wc.y, zv2.y, acc2);
        acc2 = fdot2(wc.z, zv2.z, acc2); acc2 = fdot2(wc.w, zv2.w, acc2);
        acc3 = fdot2(wc.x, zv3.x, acc3); acc3 = fdot2(wc.y, zv3.y, acc3);
        acc3 = fdot2(wc.z, zv3.z, acc3); acc3 = fdot2(wc.w, zv3.w, acc3);
      }
      _Float16* sgp = gh ? sgB : sgA;
      sgp[       gg] = (_Float16)acc0;
      sgp[ 512 + gg] = (_Float16)acc1;
      sgp[1024 + gg] = (_Float16)acc2;
      sgp[1536 + gg] = (_Float16)acc3;
    }
    __syncthreads();
    // P6: LSTM pointwise update (tid<512: 4 bi x 128 p); s in register
    if (tid < 512){
      int bi = tid>>7, p = tid&127;
      float ig = (float)sgA[bi*512+p]       + (float)sgB[bi*512+p];
      float fg = (float)sgA[bi*512+128+p]   + (float)sgB[bi*512+128+p];
      float gg_= (float)sgA[bi*512+256+p]   + (float)sgB[bi*512+256+p];
      float og = (float)sgA[bi*512+384+p]   + (float)sgB[bi*512+384+p];
      float sn = sigmoid_f(fg)*s_reg + sigmoid_f(ig)*tanh_f(gg_);
      float dn = sigmoid_f(og)*tanh_f(sn);
      s_reg = sn;
      sq16[bi*256+p]      = (_Float16)dn;   // q = [d|s] for P1
      sq16[bi*256+128+p]  = (_Float16)sn;
      sz16[bi*256+128+p]  = (_Float16)dn;   // z = [c|d] for P5
      if (step==TM-1) dT[(size_t)(b0+bi)*128+p]=dn;
    }
    __syncthreads();
  }
}

// ---------- kernel 3: skip GRU, 8 rows/block, 9 steps ----------
__global__ __launch_bounds__(256)
void gru_kernel(const u16* __restrict__ Hb, const float* __restrict__ wih,
                const float* __restrict__ whh, const float* __restrict__ bihp,
                const float* __restrict__ bhhp, float* __restrict__ hskip)
{
  __shared__ float sWih[96][101];
  __shared__ float sWhh[96][33];
  __shared__ float sxt[8][100];
  __shared__ float sh[8][33];
  const int tid = threadIdx.x;
  for (int i=tid;i<9600;i+=256){ sWih[i/100][i%100]=wih[i]; }
  for (int i=tid;i<3072;i+=256){ sWhh[i>>5][i&31]=whh[i]; }
  const int r = tid>>5, j = tid&31;
  const int rowg = blockIdx.x*8 + r;
  const int b = rowg/10, sk = rowg - b*10;
  const float b_r = bihp[j], b_z = bihp[32+j], b_n = bihp[64+j];
  const float hb_r = bhhp[j], hb_z = bhhp[32+j], hb_n = bhhp[64+j];
  sh[r][j]=0.f;
  float h = 0.f;
  __syncthreads();
  for (int pt=0; pt<9; pt++){
    for (int i=tid;i<800;i+=256){
      int rr=i/100, m=i-rr*100;
      int rg = blockIdx.x*8+rr; int bb=rg/10, ss=rg-bb*10;
      sxt[rr][m] = bf2f(Hb[(size_t)bb*9400 + (size_t)(4+pt*10+ss)*100 + m]);
    }
    __syncthreads();
    float gi_r=b_r, gi_z=b_z, gi_n=b_n, gh_r=hb_r, gh_z=hb_z, gh_n=hb_n;
    #pragma unroll 4
    for (int m=0;m<100;m++){
      float x = sxt[r][m];
      gi_r += sWih[j][m]*x; gi_z += sWih[32+j][m]*x; gi_n += sWih[64+j][m]*x;
    }
    #pragma unroll
    for (int k=0;k<32;k++){
      float hp = sh[r][k];
      gh_r += sWhh[j][k]*hp; gh_z += sWhh[32+j][k]*hp; gh_n += sWhh[64+j][k]*hp;
    }
    float rg_ = sigmoid_f(gi_r+gh_r);
    float z  = sigmoid_f(gi_z+gh_z);
    float n  = tanh_f(gi_n + rg_*gh_n);
    h = (1.f-z)*n + z*h;
    __syncthreads();
    sh[r][j]=h;
    __syncthreads();
  }
  hskip[(size_t)b*320 + sk*32 + j] = h;
}

// ---------- kernel 4: output MLP head, 32 batches/block, w1 tiled via LDS ----------
#define OUT_NB 32
#define OUT_LDS ((OUT_NB*552 + 8*552)*4)   // 88320 bytes

__global__ __launch_bounds__(256)
void out_kernel(const float* __restrict__ dT, const float* __restrict__ cLast,
                const float* __restrict__ hskip, const float* __restrict__ w1,
                const float* __restrict__ b1, const float* __restrict__ w2,
                const float* __restrict__ b2, float* __restrict__ outp)
{
  extern __shared__ float osm[];
  float* sf = osm;                 // [32][552]
  float* sw = osm + OUT_NB*552;    // [8][552]
  const int tid = threadIdx.x;
  const int b0 = blockIdx.x*OUT_NB;
  for (int i=tid;i<OUT_NB*548;i+=256){
    int bl = i/548, k = i - 548*bl; int b = b0+bl;
    float v;
    if (k<128) v = dT[(size_t)b*128+k];
    else if (k<228) v = cLast[(size_t)b*100+(k-128)];
    else v = hskip[(size_t)b*320+(k-228)];
    sf[bl*552+k]=v;
  }
  const int bl = tid>>3, j = tid&7;
  float outv = 0.f;
  for (int jt=0; jt<128; jt+=8){
    __syncthreads();
    for (int i=tid;i<8*548;i+=256){
      int rr=i/548, c=i-548*rr;
      sw[rr*552+c] = w1[(size_t)jt*548 + i];
    }
    __syncthreads();
    float acc = b1[jt+j];
    const float* fr = sf + bl*552;
    const float* wr = sw + j*552;
    #pragma unroll 4
    for (int k=0;k<548;k++) acc += fr[k]*wr[k];
    outv += fmaxf(acc,0.f)*w2[jt+j];
  }
  outv += __shfl_xor(outv,1);
  outv += __shfl_xor(outv,2);
  outv += __shfl_xor(outv,4);
  if (j==0) outp[b0+bl] = outv + b2[0];
}

// ---------- launcher ----------
extern "C" void kernel_launch(void* const* d_in, const int* in_sizes, int n_in,
                              void* d_out, int out_size, void* d_ws, size_t ws_size,
                              hipStream_t stream)
{
  const float* enc      = (const float*)d_in[0];
  const float* conv_w   = (const float*)d_in[1];
  const float* conv_b   = (const float*)d_in[2];
  const float* Wd       = (const float*)d_in[3];
  const float* Ud       = (const float*)d_in[4];
  const float* vd       = (const float*)d_in[5];
  const float* lstm_wih = (const float*)d_in[6];
  const float* lstm_whh = (const float*)d_in[7];
  const float* lstm_bih = (const float*)d_in[8];
  const float* lstm_bhh = (const float*)d_in[9];
  const float* gru_wih  = (const float*)d_in[10];
  const float* gru_whh  = (const float*)d_in[11];
  const float* gru_bih  = (const float*)d_in[12];
  const float* gru_bhh  = (const float*)d_in[13];
  const float* out1_w   = (const float*)d_in[14];
  const float* out1_b   = (const float*)d_in[15];
  const float* out2_w   = (const float*)d_in[16];
  const float* out2_b   = (const float*)d_in[17];

  char* ws = (char*)d_ws;
  u16*   Hb    = (u16*)ws;                         // 4096*9400*2 = 77,004,800 B
  float* dT    = (float*)(ws + 77004800);          // 4096*128*4  =  2,097,152 B
  float* cLast = (float*)(ws + 79101952);          // 4096*100*4  =  1,638,400 B
  float* hskip = (float*)(ws + 80740352);          // 4096*320*4  =  5,242,880 B
  // WgT aliases hskip (hskip is dead until gru_kernel runs, which is after decoder)
  uint4* WgT   = (uint4*)(ws + 80740352);          // 16*1024*16  =    262,144 B

  prep_kernel<<<64, 256, 0, stream>>>(lstm_wih, lstm_whh, WgT);

  conv_kernel<<<dim3(10,4096,1), 128, 0, stream>>>(enc, conv_w, conv_b, Hb);

  (void)hipFuncSetAttribute((const void*)decoder_kernel,
                            hipFuncAttributeMaxDynamicSharedMemorySize, DEC_LDS);
  decoder_kernel<<<4096/NB, DEC_NT, DEC_LDS, stream>>>(Hb, Wd, Ud, vd, WgT,
                                                       lstm_bih, lstm_bhh,
                                                       dT, cLast);

  gru_kernel<<<5120, 256, 0, stream>>>(Hb, gru_wih, gru_whh, gru_bih, gru_bhh, hskip);

  (void)hipFuncSetAttribute((const void*)out_kernel,
                            hipFuncAttributeMaxDynamicSharedMemorySize, OUT_LDS);
  out_kernel<<<4096/OUT_NB, 256, OUT_LDS, stream>>>(dT, cLast, hskip, out1_w, out1_b,
                                                    out2_w, out2_b, (float*)d_out);
}